// Round 9
// baseline (569.578 us; speedup 1.0000x reference)
//
#include <hip/hip_runtime.h>
#include <math.h>

#define HID 128
#define GRP 256
#define INF 9
#define OUTF 10

typedef _Float16 half8 __attribute__((ext_vector_type(8)));
typedef __attribute__((ext_vector_type(4))) float f32x4;

// ---------------- histogram over dst + fold in W-prep (layers 1..3) ----------------
// W fragment order: off = (((nt*4+kc)*4+quad)*16 + l16)*8 + j ; n=nt*16+l16, k=kc*32+quad*8+j
__global__ void hist_prepw_kernel(const int* __restrict__ ei, int* __restrict__ cnt, int E,
                                  const float* __restrict__ W1, const float* __restrict__ W2,
                                  const float* __restrict__ W3,
                                  _Float16* __restrict__ Whi, _Float16* __restrict__ Wlo) {
    int e = blockIdx.x * 256 + threadIdx.x;
    if (e < E) atomicAdd(&cnt[ei[E + e]], 1);
    if (blockIdx.x < 192) {
        int l = blockIdx.x >> 6;                       // 0..2 -> layers 1..3
        int idx = (blockIdx.x & 63) * 256 + threadIdx.x;   // 0..16383
        const float* W = (l == 0) ? W1 : (l == 1) ? W2 : W3;
        int nn = idx >> 7, k = idx & 127;
        float w = W[k * HID + nn];
        _Float16 hi = (_Float16)w;
        _Float16 lo = (_Float16)(w - (float)hi);
        int nt = nn >> 4, l16 = nn & 15;
        int kc = k >> 5, quad = (k >> 3) & 3, j = k & 7;
        size_t off = (size_t)(l + 1) * HID * HID +
                     ((((nt * 4 + kc) * 4 + quad) * 16 + l16) * 8 + j);
        Whi[off] = hi;
        Wlo[off] = lo;
    }
}

// ---------------- parallel scan phase A: per-1024-chunk sums ----------------
__global__ __launch_bounds__(256) void scanA_kernel(const int* __restrict__ cnt,
                                                    int* __restrict__ bsum, int n) {
    int tid = threadIdx.x;
    int base = blockIdx.x * 1024 + tid * 4;
    int s = 0;
    #pragma unroll
    for (int i = 0; i < 4; i++) s += (base + i < n) ? cnt[base + i] : 0;
    #pragma unroll
    for (int off = 32; off > 0; off >>= 1) s += __shfl_down(s, off);
    __shared__ int ws[4];
    if ((tid & 63) == 0) ws[tid >> 6] = s;
    __syncthreads();
    if (tid == 0) bsum[blockIdx.x] = ws[0] + ws[1] + ws[2] + ws[3];
}

// ---------------- phase B: exclusive scan of block sums (in place) ----------------
__global__ void scanB_kernel(int* __restrict__ bsum, int* __restrict__ row_ptr,
                             int nb, int n) {
    int lane = threadIdx.x;   // 64 threads
    int carry = 0;
    for (int base = 0; base < nb; base += 64) {
        int v = (base + lane < nb) ? bsum[base + lane] : 0;
        int ps = v;
        #pragma unroll
        for (int off = 1; off < 64; off <<= 1) {
            int t = __shfl_up(ps, off);
            if (lane >= off) ps += t;
        }
        if (base + lane < nb) bsum[base + lane] = carry + ps - v;
        carry += __shfl(ps, 63);
    }
    if (lane == 0) row_ptr[n] = carry;
}

// ---------------- phase C: local scan + row_ptr/cursor/dinv + graph bounds ----------------
__global__ __launch_bounds__(256) void scanC_kernel(const int* __restrict__ cnt,
                                                    const int* __restrict__ bsum,
                                                    const int* __restrict__ batch,
                                                    int* __restrict__ row_ptr,
                                                    int* __restrict__ cursor,
                                                    float* __restrict__ dinv,
                                                    int* __restrict__ gstart,
                                                    int* __restrict__ gend, int n) {
    int tid = threadIdx.x;
    int lane = tid & 63, wid = tid >> 6;
    int idx0 = blockIdx.x * 1024 + tid * 4;
    int v[4];
    #pragma unroll
    for (int i = 0; i < 4; i++) v[i] = (idx0 + i < n) ? cnt[idx0 + i] : 0;
    int s = v[0] + v[1] + v[2] + v[3];
    int ps = s;
    #pragma unroll
    for (int off = 1; off < 64; off <<= 1) {
        int t = __shfl_up(ps, off);
        if (lane >= off) ps += t;
    }
    __shared__ int wsum[4];
    if (lane == 63) wsum[wid] = ps;
    __syncthreads();
    int woff = 0;
    #pragma unroll
    for (int i = 0; i < 4; i++) if (i < wid) woff += wsum[i];
    int run = bsum[blockIdx.x] + woff + (ps - s);
    #pragma unroll
    for (int i = 0; i < 4; i++) {
        int idx = idx0 + i;
        if (idx < n) {
            row_ptr[idx] = run;
            cursor[idx] = run;
            dinv[idx] = rsqrtf((float)(v[i] + 1));
            run += v[i];
            int b = batch[idx];
            if (idx == 0 || batch[idx - 1] != b) gstart[b] = idx;
            if (idx == n - 1 || batch[idx + 1] != b) gend[b] = idx + 1;
        }
    }
}

// ---------------- CSR fill: (src, coef) packed as int2, one 8B scatter ----------------
__global__ void fill_kernel(const int* __restrict__ ei, int* __restrict__ cursor,
                            const float* __restrict__ dinv,
                            int2* __restrict__ csr, int E) {
    int e = blockIdx.x * blockDim.x + threadIdx.x;
    if (e >= E) return;
    int s = ei[e], d = ei[E + e];
    int pos = atomicAdd(&cursor[d], 1);
    csr[pos] = make_int2(s, __float_as_int(dinv[s] * dinv[d]));
}

// ---------------- rational activation ----------------
__device__ __forceinline__ float rational_act(float xv, const float* __restrict__ a,
                                              const float* __restrict__ q) {
    float P = a[5];
    P = fmaf(P, xv, a[4]); P = fmaf(P, xv, a[3]); P = fmaf(P, xv, a[2]);
    P = fmaf(P, xv, a[1]); P = fmaf(P, xv, a[0]);
    float Q = q[3];
    Q = fmaf(Q, xv, q[2]); Q = fmaf(Q, xv, q[1]); Q = fmaf(Q, xv, q[0]);
    Q *= xv;
    return P / (1.0f + fabsf(Q));
}

// ---------------- aggregate x (9 channels) + cagg ----------------
__global__ __launch_bounds__(256) void aggx_kernel(const float* __restrict__ x,
                                                   const int* __restrict__ row_ptr,
                                                   const int2* __restrict__ csr,
                                                   const float* __restrict__ dinv,
                                                   float* __restrict__ aggX,
                                                   float* __restrict__ cagg, int n) {
    int tid = threadIdx.x;
    int node = blockIdx.x * 16 + (tid >> 4);
    int lane = tid & 15;
    if (node >= n) return;
    float di = dinv[node];
    float self = di * di;
    float acc = (lane < INF) ? x[node * INF + lane] * self : 0.0f;
    float cfs = self;
    int beg = row_ptr[node], end = row_ptr[node + 1];
    for (int j = beg; j < end; j++) {
        int2 p = csr[j];
        float cf = __int_as_float(p.y);
        cfs += cf;
        if (lane < INF) acc = fmaf(cf, x[p.x * INF + lane], acc);
    }
    if (lane < INF) aggX[node * INF + lane] = acc;
    if (lane == 0) cagg[node] = cfs;
}

// ---------------- layer-0: aggX(Nx9) @ W0 + b0 -> rational -> act(fp16) + stats ----------------
__global__ __launch_bounds__(256) void gemm0_fused_kernel(const float* __restrict__ aggX,
                                                          const float* __restrict__ W0,
                                                          const float* __restrict__ b0,
                                                          const float* __restrict__ rat_num,
                                                          const float* __restrict__ rat_den,
                                                          const int* __restrict__ cl_assign,
                                                          _Float16* __restrict__ act,
                                                          float* __restrict__ stat, int n) {
    __shared__ float Ws[INF * HID];
    __shared__ float s_num[120], s_den[80];
    __shared__ int s_cl[HID];
    __shared__ float s_b[HID];
    __shared__ float s_sum[HID], s_sq[HID];
    int tid = threadIdx.x;
    for (int i = tid; i < INF * HID; i += 256) Ws[i] = W0[i];
    if (tid < 120) s_num[tid] = rat_num[tid];
    if (tid < 80) s_den[tid] = rat_den[tid];
    if (tid < HID) {
        s_cl[tid] = cl_assign[tid];
        s_b[tid] = b0[tid];
        s_sum[tid] = 0.0f; s_sq[tid] = 0.0f;
    }
    __syncthreads();
    int c = tid & 127;
    int half = tid >> 7;
    const float* a = s_num + s_cl[c] * 6;
    const float* q = s_den + s_cl[c] * 4;
    float psum = 0.0f, psq = 0.0f;
    for (int node = blockIdx.x * 2 + half; node < n; node += gridDim.x * 2) {
        float acc = s_b[c];
        #pragma unroll
        for (int k = 0; k < INF; k++) acc = fmaf(aggX[node * INF + k], Ws[k * HID + c], acc);
        float r = rational_act(acc, a, q);
        act[node * HID + c] = (_Float16)r;
        psum += r; psq = fmaf(r, r, psq);
    }
    atomicAdd(&s_sum[c], psum);
    atomicAdd(&s_sq[c], psq);
    __syncthreads();
    if (tid < HID) {
        atomicAdd(&stat[tid], s_sum[tid]);
        atomicAdd(&stat[HID + tid], s_sq[tid]);
    }
}

// ---------------- fused layer (1-3): gather-agg -> LDS A-tile -> fp16 MFMA -> rational ----------------
// 512 threads, 32 rows/block; one (node x 8ch) slice per thread.
// __launch_bounds__(512,4): VGPR cap 128 so the 8-wide gather load batch stays in flight
// (r8's (512,8) capped VGPR at 32 and serialized the loads — 100 µs vs 81).
// Ping-pong in/out buffers (in-place is a cross-block race).
__global__ __launch_bounds__(512, 4) void layer_fused_kernel(const _Float16* __restrict__ act,
                                                          const int2* __restrict__ csr,
                                                          const int* __restrict__ row_ptr,
                                                          const float* __restrict__ dinv,
                                                          const float* __restrict__ cagg,
                                                          const float* __restrict__ statPrev,
                                                          const float* __restrict__ gPrev,
                                                          const float* __restrict__ bePrev,
                                                          const _Float16* __restrict__ Whi,
                                                          const _Float16* __restrict__ Wlo,
                                                          const float* __restrict__ bias,
                                                          const float* __restrict__ rat_num,
                                                          const float* __restrict__ rat_den,
                                                          const int* __restrict__ cl_assign,
                                                          _Float16* __restrict__ actOut,
                                                          float* __restrict__ statOut, int n) {
    __shared__ _Float16 Alds[32 * 136];
    __shared__ int2 s_pair[32][16];
    __shared__ float s_bnw[HID], s_bnu[HID];
    __shared__ float s_num[120], s_den[80];
    __shared__ int s_cl[HID];
    __shared__ float s_bias[HID];
    __shared__ float s_sum[HID], s_sq[HID];
    int tid = threadIdx.x;
    if (tid < 120) s_num[tid] = rat_num[tid];
    if (tid < 80) s_den[tid] = rat_den[tid];
    if (tid < HID) {
        float inv_n = 1.0f / (float)n;
        float mean = statPrev[tid] * inv_n;
        float var = statPrev[HID + tid] * inv_n - mean * mean;
        float w = gPrev[tid] * rsqrtf(var + 1e-5f);
        s_bnw[tid] = w;
        s_bnu[tid] = bePrev[tid] - mean * w;
        s_cl[tid] = cl_assign[tid];
        s_bias[tid] = bias[tid];
        s_sum[tid] = 0.0f; s_sq[tid] = 0.0f;
    }
    __syncthreads();

    int r0 = blockIdx.x * 32;
    int grp = tid >> 4, glane = tid & 15;      // grp = local row 0..31
    const half8* act8 = (const half8*)act;

    // ---- gather phase: one node-slice per thread, 8 loads in flight ----
    {
        int node = r0 + grp;
        half8 o;
        if (node < n) {
            float di = dinv[node];
            float selfc = di * di;
            half8 sv = act8[node * 16 + glane];
            float acc[8];
            #pragma unroll
            for (int t = 0; t < 8; t++) acc[t] = (float)sv[t] * selfc;
            int beg = row_ptr[node], end = row_ptr[node + 1];
            for (int base = beg; base < end; base += 16) {
                int m = end - base; if (m > 16) m = 16;
                if (glane < m) s_pair[grp][glane] = csr[base + glane];
                __builtin_amdgcn_wave_barrier();
                int j = 0;
                for (; j + 8 <= m; j += 8) {
                    int2 p0 = s_pair[grp][j],     p1 = s_pair[grp][j + 1];
                    int2 p2 = s_pair[grp][j + 2], p3 = s_pair[grp][j + 3];
                    int2 p4 = s_pair[grp][j + 4], p5 = s_pair[grp][j + 5];
                    int2 p6 = s_pair[grp][j + 6], p7 = s_pair[grp][j + 7];
                    half8 v0 = act8[p0.x * 16 + glane];
                    half8 v1 = act8[p1.x * 16 + glane];
                    half8 v2 = act8[p2.x * 16 + glane];
                    half8 v3 = act8[p3.x * 16 + glane];
                    half8 v4 = act8[p4.x * 16 + glane];
                    half8 v5 = act8[p5.x * 16 + glane];
                    half8 v6 = act8[p6.x * 16 + glane];
                    half8 v7 = act8[p7.x * 16 + glane];
                    float c0 = __int_as_float(p0.y), c1 = __int_as_float(p1.y);
                    float c2 = __int_as_float(p2.y), c3 = __int_as_float(p3.y);
                    float c4 = __int_as_float(p4.y), c5 = __int_as_float(p5.y);
                    float c6 = __int_as_float(p6.y), c7 = __int_as_float(p7.y);
                    #pragma unroll
                    for (int t = 0; t < 8; t++) {
                        acc[t] = fmaf(c0, (float)v0[t], acc[t]);
                        acc[t] = fmaf(c1, (float)v1[t], acc[t]);
                        acc[t] = fmaf(c2, (float)v2[t], acc[t]);
                        acc[t] = fmaf(c3, (float)v3[t], acc[t]);
                        acc[t] = fmaf(c4, (float)v4[t], acc[t]);
                        acc[t] = fmaf(c5, (float)v5[t], acc[t]);
                        acc[t] = fmaf(c6, (float)v6[t], acc[t]);
                        acc[t] = fmaf(c7, (float)v7[t], acc[t]);
                    }
                }
                for (; j + 4 <= m; j += 4) {
                    int2 p0 = s_pair[grp][j],     p1 = s_pair[grp][j + 1];
                    int2 p2 = s_pair[grp][j + 2], p3 = s_pair[grp][j + 3];
                    half8 v0 = act8[p0.x * 16 + glane];
                    half8 v1 = act8[p1.x * 16 + glane];
                    half8 v2 = act8[p2.x * 16 + glane];
                    half8 v3 = act8[p3.x * 16 + glane];
                    float c0 = __int_as_float(p0.y), c1 = __int_as_float(p1.y);
                    float c2 = __int_as_float(p2.y), c3 = __int_as_float(p3.y);
                    #pragma unroll
                    for (int t = 0; t < 8; t++) {
                        acc[t] = fmaf(c0, (float)v0[t], acc[t]);
                        acc[t] = fmaf(c1, (float)v1[t], acc[t]);
                        acc[t] = fmaf(c2, (float)v2[t], acc[t]);
                        acc[t] = fmaf(c3, (float)v3[t], acc[t]);
                    }
                }
                for (; j < m; j++) {
                    int2 p = s_pair[grp][j];
                    float cf = __int_as_float(p.y);
                    half8 v = act8[p.x * 16 + glane];
                    #pragma unroll
                    for (int t = 0; t < 8; t++) acc[t] = fmaf(cf, (float)v[t], acc[t]);
                }
                __builtin_amdgcn_wave_barrier();
            }
            float cg = cagg[node];
            #pragma unroll
            for (int t = 0; t < 8; t++) {
                int c = glane * 8 + t;
                o[t] = (_Float16)fmaf(s_bnw[c], acc[t], s_bnu[c] * cg);
            }
        } else {
            #pragma unroll
            for (int t = 0; t < 8; t++) o[t] = (_Float16)0.0f;
        }
        *(half8*)&Alds[grp * 136 + glane * 8] = o;
    }
    __syncthreads();

    // ---- MFMA phase: 8 waves; wave w -> m-tile (w&1), n-tiles 2*(w>>1), 2*(w>>1)+1 ----
    int w = tid >> 6, l64 = tid & 63;
    int quad = l64 >> 4, l16 = l64 & 15;
    int mtile = w & 1, npair = w >> 1;
    const half8* Bh8 = (const half8*)Whi;
    const half8* Bl8 = (const half8*)Wlo;
    f32x4 acc0 = (f32x4){0.f, 0.f, 0.f, 0.f};
    f32x4 acc1 = (f32x4){0.f, 0.f, 0.f, 0.f};
    int lrowA = mtile * 16 + l16;
    #pragma unroll
    for (int kc = 0; kc < 4; kc++) {
        half8 a = *(const half8*)&Alds[lrowA * 136 + kc * 32 + quad * 8];
        int nt0 = npair * 2, nt1 = npair * 2 + 1;
        half8 bh0 = Bh8[(nt0 * 4 + kc) * 64 + l64];
        half8 bl0 = Bl8[(nt0 * 4 + kc) * 64 + l64];
        half8 bh1 = Bh8[(nt1 * 4 + kc) * 64 + l64];
        half8 bl1 = Bl8[(nt1 * 4 + kc) * 64 + l64];
        acc0 = __builtin_amdgcn_mfma_f32_16x16x32_f16(a, bh0, acc0, 0, 0, 0);
        acc0 = __builtin_amdgcn_mfma_f32_16x16x32_f16(a, bl0, acc0, 0, 0, 0);
        acc1 = __builtin_amdgcn_mfma_f32_16x16x32_f16(a, bh1, acc1, 0, 0, 0);
        acc1 = __builtin_amdgcn_mfma_f32_16x16x32_f16(a, bl1, acc1, 0, 0, 0);
    }

    // ---- epilogue: bias + rational + fp16 store + stats (C layout: col=l16, row=quad*4+reg) ----
    float ps0 = 0.f, pq0 = 0.f, ps1 = 0.f, pq1 = 0.f;
    int col0 = (npair * 2) * 16 + l16;
    int col1 = (npair * 2 + 1) * 16 + l16;
    #pragma unroll
    for (int reg = 0; reg < 4; reg++) {
        int row = r0 + mtile * 16 + quad * 4 + reg;
        if (row < n) {
            float v0 = acc0[reg] + s_bias[col0];
            float r0v = rational_act(v0, s_num + s_cl[col0] * 6, s_den + s_cl[col0] * 4);
            actOut[row * HID + col0] = (_Float16)r0v;
            ps0 += r0v; pq0 = fmaf(r0v, r0v, pq0);
            float v1 = acc1[reg] + s_bias[col1];
            float r1v = rational_act(v1, s_num + s_cl[col1] * 6, s_den + s_cl[col1] * 4);
            actOut[row * HID + col1] = (_Float16)r1v;
            ps1 += r1v; pq1 = fmaf(r1v, r1v, pq1);
        }
    }
    atomicAdd(&s_sum[col0], ps0);
    atomicAdd(&s_sq[col0], pq0);
    atomicAdd(&s_sum[col1], ps1);
    atomicAdd(&s_sq[col1], pq1);
    __syncthreads();
    if (tid < HID) {
        atomicAdd(&statOut[tid], s_sum[tid]);
        atomicAdd(&statOut[HID + tid], s_sq[tid]);
    }
}

// ---------------- fused pool (+final BN affine from stats) + 3-stage MLP ----------------
__global__ __launch_bounds__(256) void poolmlp_kernel(const _Float16* __restrict__ act,
                                                      const int* __restrict__ gstart,
                                                      const int* __restrict__ gend,
                                                      const float* __restrict__ stat,
                                                      const float* __restrict__ g3,
                                                      const float* __restrict__ be3,
                                                      const float* __restrict__ HW1,
                                                      const float* __restrict__ Hb1,
                                                      const float* __restrict__ HW2,
                                                      const float* __restrict__ Hb2,
                                                      const float* __restrict__ HW3,
                                                      const float* __restrict__ Hb3,
                                                      float* __restrict__ out, int n) {
    __shared__ float red[16][HID];
    __shared__ float s_pool[HID];
    __shared__ float s_z[HID];
    int gi = blockIdx.x;
    int tid = threadIdx.x;
    int rg = tid >> 4, lane = tid & 15;
    int s = gstart[gi], e = gend[gi];
    const half8* act8 = (const half8*)act;
    float a[8];
    #pragma unroll
    for (int t = 0; t < 8; t++) a[t] = 0.0f;
    for (int r = s + rg; r < e; r += 16) {
        half8 v = act8[r * 16 + lane];
        #pragma unroll
        for (int t = 0; t < 8; t++) a[t] += (float)v[t];
    }
    #pragma unroll
    for (int t = 0; t < 8; t++) red[rg][lane * 8 + t] = a[t];
    __syncthreads();
    if (tid < HID) {
        float tot = 0.0f;
        #pragma unroll
        for (int i = 0; i < 16; i++) tot += red[i][tid];
        int cnt = e - s;
        float pooled = 0.0f;
        if (cnt > 0) {
            float inv_n = 1.0f / (float)n;
            float mean = stat[tid] * inv_n;
            float var = stat[HID + tid] * inv_n - mean * mean;
            float w = g3[tid] * rsqrtf(var + 1e-5f);
            float u = be3[tid] - mean * w;
            pooled = fmaf(w, tot / (float)cnt, u);
        }
        s_pool[tid] = pooled;
    }
    __syncthreads();
    if (tid < HID) {
        float acc = Hb1[tid];
        #pragma unroll 8
        for (int k = 0; k < HID; k++) acc = fmaf(s_pool[k], HW1[k * HID + tid], acc);
        s_z[tid] = 0.5f * acc * (1.0f + erff(acc * 0.70710678118654752f));
    }
    __syncthreads();
    if (tid < HID) {
        float acc = Hb2[tid];
        #pragma unroll 8
        for (int k = 0; k < HID; k++) acc = fmaf(s_z[k], HW2[k * HID + tid], acc);
        s_pool[tid] = 0.5f * acc * (1.0f + erff(acc * 0.70710678118654752f));
    }
    __syncthreads();
    if (tid < OUTF) {
        float acc = Hb3[tid];
        #pragma unroll 8
        for (int k = 0; k < HID; k++) acc = fmaf(s_pool[k], HW3[k * OUTF + tid], acc);
        out[gi * OUTF + tid] = acc;
    }
}

extern "C" void kernel_launch(void* const* d_in, const int* in_sizes, int n_in,
                              void* d_out, int out_size, void* d_ws, size_t ws_size,
                              hipStream_t stream) {
    const float* x          = (const float*)d_in[0];
    const int*   edge_index = (const int*)d_in[1];
    const int*   batch      = (const int*)d_in[2];
    const float* W[4]  = {(const float*)d_in[3], (const float*)d_in[7], (const float*)d_in[11], (const float*)d_in[15]};
    const float* bL[4] = {(const float*)d_in[4], (const float*)d_in[8], (const float*)d_in[12], (const float*)d_in[16]};
    const float* gL[4] = {(const float*)d_in[5], (const float*)d_in[9], (const float*)d_in[13], (const float*)d_in[17]};
    const float* beL[4]= {(const float*)d_in[6], (const float*)d_in[10], (const float*)d_in[14], (const float*)d_in[18]};
    const float* rat_num = (const float*)d_in[19];
    const float* rat_den = (const float*)d_in[20];
    const int*   cl_assign = (const int*)d_in[21];
    const float* HW1 = (const float*)d_in[22];
    const float* Hb1 = (const float*)d_in[23];
    const float* HW2 = (const float*)d_in[24];
    const float* Hb2 = (const float*)d_in[25];
    const float* HW3 = (const float*)d_in[26];
    const float* Hb3 = (const float*)d_in[27];
    float* out = (float*)d_out;

    const int N = in_sizes[0] / INF;
    const int E = in_sizes[1] / 2;
    const int NB = (N + 1023) / 1024;

    // ---- workspace layout (dword offsets) ----
    char* wsb = (char*)d_ws;
    size_t o = 0;
    #define ALIGN16 o = (o + 3) & ~(size_t)3;
    int*   cnt     = (int*)(wsb + o * 4);  o += N; ALIGN16          // zeroed; reused as cagg
    int*   gstart  = (int*)(wsb + o * 4);  o += GRP;                // zeroed
    int*   gend    = (int*)(wsb + o * 4);  o += GRP;                // zeroed
    float* bnstat  = (float*)(wsb + o * 4); o += 4 * 256;           // zeroed
    size_t zero_elems = o;
    int*   bsum    = (int*)(wsb + o * 4);  o += ((NB + 63) & ~63); ALIGN16
    int*   cursor  = (int*)(wsb + o * 4);  o += N; ALIGN16
    int*   row_ptr = (int*)(wsb + o * 4);  o += N + 1; ALIGN16
    float* dinv    = (float*)(wsb + o * 4); o += N; ALIGN16
    int2*  csr     = (int2*)(wsb + o * 4);  o += 2 * (size_t)E; ALIGN16
    float* aggX    = (float*)(wsb + o * 4); o += (size_t)N * INF; ALIGN16
    _Float16* WhiAll = (_Float16*)(wsb + o * 4); o += 4 * HID * HID / 2; ALIGN16
    _Float16* WloAll = (_Float16*)(wsb + o * 4); o += 4 * HID * HID / 2; ALIGN16
    _Float16* actA   = (_Float16*)(wsb + o * 4); o += (size_t)N * HID / 2; ALIGN16
    _Float16* actB   = (_Float16*)(wsb + o * 4); o += (size_t)N * HID / 2;
    float* cagg = (float*)cnt;

    hipMemsetAsync(d_ws, 0, zero_elems * 4, stream);

    int eb = (E + 255) / 256;
    hist_prepw_kernel<<<eb, 256, 0, stream>>>(edge_index, cnt, E, W[1], W[2], W[3],
                                              WhiAll, WloAll);
    scanA_kernel<<<NB, 256, 0, stream>>>(cnt, bsum, N);
    scanB_kernel<<<1, 64, 0, stream>>>(bsum, row_ptr, NB, N);
    scanC_kernel<<<NB, 256, 0, stream>>>(cnt, bsum, batch, row_ptr, cursor, dinv,
                                         gstart, gend, N);
    fill_kernel<<<eb, 256, 0, stream>>>(edge_index, cursor, dinv, csr, E);

    // layer 0
    aggx_kernel<<<(N + 15) / 16, 256, 0, stream>>>(x, row_ptr, csr, dinv, aggX, cagg, N);
    gemm0_fused_kernel<<<1024, 256, 0, stream>>>(aggX, W[0], bL[0], rat_num, rat_den,
                                                 cl_assign, actA, bnstat, N);

    // layers 1-3: ping-pong actA <-> actB (in-place would be a cross-block race)
    _Float16* bufs[2] = {actA, actB};
    int layer_grid = (N + 31) / 32;
    for (int l = 1; l < 4; l++) {
        _Float16* src = bufs[(l - 1) & 1];
        _Float16* dst = bufs[l & 1];
        layer_fused_kernel<<<layer_grid, 512, 0, stream>>>(src, csr, row_ptr, dinv, cagg,
                                                           bnstat + (l - 1) * 256,
                                                           gL[l - 1], beL[l - 1],
                                                           WhiAll + (size_t)l * HID * HID,
                                                           WloAll + (size_t)l * HID * HID,
                                                           bL[l], rat_num, rat_den, cl_assign,
                                                           dst, bnstat + l * 256, N);
    }
    poolmlp_kernel<<<GRP, 256, 0, stream>>>(bufs[3 & 1], gstart, gend, bnstat + 3 * 256,
                                            gL[3], beL[3], HW1, Hb1, HW2, Hb2, HW3, Hb3,
                                            out, N);
}

// Round 10
// 544.312 us; speedup vs baseline: 1.0464x; 1.0464x over previous
//
#include <hip/hip_runtime.h>
#include <math.h>

#define HID 128
#define GRP 256
#define INF 9
#define OUTF 10

typedef _Float16 half8 __attribute__((ext_vector_type(8)));
typedef __attribute__((ext_vector_type(4))) float f32x4;

// ---------------- histogram over dst + fold in W-prep (layers 1..3) ----------------
// W fragment order: off = (((nt*4+kc)*4+quad)*16 + l16)*8 + j ; n=nt*16+l16, k=kc*32+quad*8+j
__global__ void hist_prepw_kernel(const int* __restrict__ ei, int* __restrict__ cnt, int E,
                                  const float* __restrict__ W1, const float* __restrict__ W2,
                                  const float* __restrict__ W3,
                                  _Float16* __restrict__ Whi, _Float16* __restrict__ Wlo) {
    int e = blockIdx.x * 256 + threadIdx.x;
    if (e < E) atomicAdd(&cnt[ei[E + e]], 1);
    if (blockIdx.x < 192) {
        int l = blockIdx.x >> 6;                       // 0..2 -> layers 1..3
        int idx = (blockIdx.x & 63) * 256 + threadIdx.x;   // 0..16383
        const float* W = (l == 0) ? W1 : (l == 1) ? W2 : W3;
        int nn = idx >> 7, k = idx & 127;
        float w = W[k * HID + nn];
        _Float16 hi = (_Float16)w;
        _Float16 lo = (_Float16)(w - (float)hi);
        int nt = nn >> 4, l16 = nn & 15;
        int kc = k >> 5, quad = (k >> 3) & 3, j = k & 7;
        size_t off = (size_t)(l + 1) * HID * HID +
                     ((((nt * 4 + kc) * 4 + quad) * 16 + l16) * 8 + j);
        Whi[off] = hi;
        Wlo[off] = lo;
    }
}

// ---------------- parallel scan phase A: per-1024-chunk sums ----------------
__global__ __launch_bounds__(256) void scanA_kernel(const int* __restrict__ cnt,
                                                    int* __restrict__ bsum, int n) {
    int tid = threadIdx.x;
    int base = blockIdx.x * 1024 + tid * 4;
    int s = 0;
    #pragma unroll
    for (int i = 0; i < 4; i++) s += (base + i < n) ? cnt[base + i] : 0;
    #pragma unroll
    for (int off = 32; off > 0; off >>= 1) s += __shfl_down(s, off);
    __shared__ int ws[4];
    if ((tid & 63) == 0) ws[tid >> 6] = s;
    __syncthreads();
    if (tid == 0) bsum[blockIdx.x] = ws[0] + ws[1] + ws[2] + ws[3];
}

// ---------------- phase B: exclusive scan of block sums (in place) ----------------
__global__ void scanB_kernel(int* __restrict__ bsum, int* __restrict__ row_ptr,
                             int nb, int n) {
    int lane = threadIdx.x;   // 64 threads
    int carry = 0;
    for (int base = 0; base < nb; base += 64) {
        int v = (base + lane < nb) ? bsum[base + lane] : 0;
        int ps = v;
        #pragma unroll
        for (int off = 1; off < 64; off <<= 1) {
            int t = __shfl_up(ps, off);
            if (lane >= off) ps += t;
        }
        if (base + lane < nb) bsum[base + lane] = carry + ps - v;
        carry += __shfl(ps, 63);
    }
    if (lane == 0) row_ptr[n] = carry;
}

// ---------------- phase C: local scan + row_ptr/cursor/dinv + graph bounds ----------------
__global__ __launch_bounds__(256) void scanC_kernel(const int* __restrict__ cnt,
                                                    const int* __restrict__ bsum,
                                                    const int* __restrict__ batch,
                                                    int* __restrict__ row_ptr,
                                                    int* __restrict__ cursor,
                                                    float* __restrict__ dinv,
                                                    int* __restrict__ gstart,
                                                    int* __restrict__ gend, int n) {
    int tid = threadIdx.x;
    int lane = tid & 63, wid = tid >> 6;
    int idx0 = blockIdx.x * 1024 + tid * 4;
    int v[4];
    #pragma unroll
    for (int i = 0; i < 4; i++) v[i] = (idx0 + i < n) ? cnt[idx0 + i] : 0;
    int s = v[0] + v[1] + v[2] + v[3];
    int ps = s;
    #pragma unroll
    for (int off = 1; off < 64; off <<= 1) {
        int t = __shfl_up(ps, off);
        if (lane >= off) ps += t;
    }
    __shared__ int wsum[4];
    if (lane == 63) wsum[wid] = ps;
    __syncthreads();
    int woff = 0;
    #pragma unroll
    for (int i = 0; i < 4; i++) if (i < wid) woff += wsum[i];
    int run = bsum[blockIdx.x] + woff + (ps - s);
    #pragma unroll
    for (int i = 0; i < 4; i++) {
        int idx = idx0 + i;
        if (idx < n) {
            row_ptr[idx] = run;
            cursor[idx] = run;
            dinv[idx] = rsqrtf((float)(v[i] + 1));
            run += v[i];
            int b = batch[idx];
            if (idx == 0 || batch[idx - 1] != b) gstart[b] = idx;
            if (idx == n - 1 || batch[idx + 1] != b) gend[b] = idx + 1;
        }
    }
}

// ---------------- CSR fill: (src, coef) packed as int2, one 8B scatter ----------------
__global__ void fill_kernel(const int* __restrict__ ei, int* __restrict__ cursor,
                            const float* __restrict__ dinv,
                            int2* __restrict__ csr, int E) {
    int e = blockIdx.x * blockDim.x + threadIdx.x;
    if (e >= E) return;
    int s = ei[e], d = ei[E + e];
    int pos = atomicAdd(&cursor[d], 1);
    csr[pos] = make_int2(s, __float_as_int(dinv[s] * dinv[d]));
}

// ---------------- rational activation ----------------
__device__ __forceinline__ float rational_act(float xv, const float* __restrict__ a,
                                              const float* __restrict__ q) {
    float P = a[5];
    P = fmaf(P, xv, a[4]); P = fmaf(P, xv, a[3]); P = fmaf(P, xv, a[2]);
    P = fmaf(P, xv, a[1]); P = fmaf(P, xv, a[0]);
    float Q = q[3];
    Q = fmaf(Q, xv, q[2]); Q = fmaf(Q, xv, q[1]); Q = fmaf(Q, xv, q[0]);
    Q *= xv;
    return P / (1.0f + fabsf(Q));
}

// ---------------- aggregate x (9 channels) + cagg ----------------
__global__ __launch_bounds__(256) void aggx_kernel(const float* __restrict__ x,
                                                   const int* __restrict__ row_ptr,
                                                   const int2* __restrict__ csr,
                                                   const float* __restrict__ dinv,
                                                   float* __restrict__ aggX,
                                                   float* __restrict__ cagg, int n) {
    int tid = threadIdx.x;
    int node = blockIdx.x * 16 + (tid >> 4);
    int lane = tid & 15;
    if (node >= n) return;
    float di = dinv[node];
    float self = di * di;
    float acc = (lane < INF) ? x[node * INF + lane] * self : 0.0f;
    float cfs = self;
    int beg = row_ptr[node], end = row_ptr[node + 1];
    for (int j = beg; j < end; j++) {
        int2 p = csr[j];
        float cf = __int_as_float(p.y);
        cfs += cf;
        if (lane < INF) acc = fmaf(cf, x[p.x * INF + lane], acc);
    }
    if (lane < INF) aggX[node * INF + lane] = acc;
    if (lane == 0) cagg[node] = cfs;
}

// ---------------- layer-0: aggX(Nx9) @ W0 + b0 -> rational -> act(fp16) + stats ----------------
__global__ __launch_bounds__(256) void gemm0_fused_kernel(const float* __restrict__ aggX,
                                                          const float* __restrict__ W0,
                                                          const float* __restrict__ b0,
                                                          const float* __restrict__ rat_num,
                                                          const float* __restrict__ rat_den,
                                                          const int* __restrict__ cl_assign,
                                                          _Float16* __restrict__ act,
                                                          float* __restrict__ stat, int n) {
    __shared__ float Ws[INF * HID];
    __shared__ float s_num[120], s_den[80];
    __shared__ int s_cl[HID];
    __shared__ float s_b[HID];
    __shared__ float s_sum[HID], s_sq[HID];
    int tid = threadIdx.x;
    for (int i = tid; i < INF * HID; i += 256) Ws[i] = W0[i];
    if (tid < 120) s_num[tid] = rat_num[tid];
    if (tid < 80) s_den[tid] = rat_den[tid];
    if (tid < HID) {
        s_cl[tid] = cl_assign[tid];
        s_b[tid] = b0[tid];
        s_sum[tid] = 0.0f; s_sq[tid] = 0.0f;
    }
    __syncthreads();
    int c = tid & 127;
    int half = tid >> 7;
    const float* a = s_num + s_cl[c] * 6;
    const float* q = s_den + s_cl[c] * 4;
    float psum = 0.0f, psq = 0.0f;
    for (int node = blockIdx.x * 2 + half; node < n; node += gridDim.x * 2) {
        float acc = s_b[c];
        #pragma unroll
        for (int k = 0; k < INF; k++) acc = fmaf(aggX[node * INF + k], Ws[k * HID + c], acc);
        float r = rational_act(acc, a, q);
        act[node * HID + c] = (_Float16)r;
        psum += r; psq = fmaf(r, r, psq);
    }
    atomicAdd(&s_sum[c], psum);
    atomicAdd(&s_sq[c], psq);
    __syncthreads();
    if (tid < HID) {
        atomicAdd(&stat[tid], s_sum[tid]);
        atomicAdd(&stat[HID + tid], s_sq[tid]);
    }
}

// ---------------- standalone gather-aggregate (fp16) + inline BN affine -> A (fp16) ----------------
// 16 nodes/block x 16 lanes, 256 threads, default VGPR budget, 8 loads in flight.
// UNFUSED from the GEMM on purpose: fusing (r6-r9) tied gather TLP to the GEMM tile and
// its barrier coupled all waves to the slowest-degree node — 101 µs vs ~45 split.
__global__ __launch_bounds__(256) void agg_kernel(const _Float16* __restrict__ act,
                                                  const int* __restrict__ row_ptr,
                                                  const int2* __restrict__ csr,
                                                  const float* __restrict__ dinv,
                                                  const float* __restrict__ cagg,
                                                  const float* __restrict__ statPrev,
                                                  const float* __restrict__ gPrev,
                                                  const float* __restrict__ bePrev,
                                                  _Float16* __restrict__ A, int n) {
    __shared__ float s_bnw[HID], s_bnu[HID];
    __shared__ int2 s_pair[16][16];
    int tid = threadIdx.x;
    if (tid < HID) {
        float inv_n = 1.0f / (float)n;
        float mean = statPrev[tid] * inv_n;
        float var = statPrev[HID + tid] * inv_n - mean * mean;
        float w = gPrev[tid] * rsqrtf(var + 1e-5f);
        s_bnw[tid] = w;
        s_bnu[tid] = bePrev[tid] - mean * w;
    }
    __syncthreads();
    int row = tid >> 4, lane = tid & 15;
    int node = blockIdx.x * 16 + row;
    if (node >= n) return;
    const half8* act8 = (const half8*)act;
    float di = dinv[node];
    float selfc = di * di;
    half8 sv = act8[node * 16 + lane];
    float acc[8];
    #pragma unroll
    for (int t = 0; t < 8; t++) acc[t] = (float)sv[t] * selfc;
    int beg = row_ptr[node], end = row_ptr[node + 1];
    for (int base = beg; base < end; base += 16) {
        int m = end - base; if (m > 16) m = 16;
        if (lane < m) s_pair[row][lane] = csr[base + lane];
        __builtin_amdgcn_wave_barrier();
        int j = 0;
        for (; j + 8 <= m; j += 8) {
            int2 p0 = s_pair[row][j],     p1 = s_pair[row][j + 1];
            int2 p2 = s_pair[row][j + 2], p3 = s_pair[row][j + 3];
            int2 p4 = s_pair[row][j + 4], p5 = s_pair[row][j + 5];
            int2 p6 = s_pair[row][j + 6], p7 = s_pair[row][j + 7];
            half8 v0 = act8[p0.x * 16 + lane];
            half8 v1 = act8[p1.x * 16 + lane];
            half8 v2 = act8[p2.x * 16 + lane];
            half8 v3 = act8[p3.x * 16 + lane];
            half8 v4 = act8[p4.x * 16 + lane];
            half8 v5 = act8[p5.x * 16 + lane];
            half8 v6 = act8[p6.x * 16 + lane];
            half8 v7 = act8[p7.x * 16 + lane];
            float c0 = __int_as_float(p0.y), c1 = __int_as_float(p1.y);
            float c2 = __int_as_float(p2.y), c3 = __int_as_float(p3.y);
            float c4 = __int_as_float(p4.y), c5 = __int_as_float(p5.y);
            float c6 = __int_as_float(p6.y), c7 = __int_as_float(p7.y);
            #pragma unroll
            for (int t = 0; t < 8; t++) {
                acc[t] = fmaf(c0, (float)v0[t], acc[t]);
                acc[t] = fmaf(c1, (float)v1[t], acc[t]);
                acc[t] = fmaf(c2, (float)v2[t], acc[t]);
                acc[t] = fmaf(c3, (float)v3[t], acc[t]);
                acc[t] = fmaf(c4, (float)v4[t], acc[t]);
                acc[t] = fmaf(c5, (float)v5[t], acc[t]);
                acc[t] = fmaf(c6, (float)v6[t], acc[t]);
                acc[t] = fmaf(c7, (float)v7[t], acc[t]);
            }
        }
        for (; j + 4 <= m; j += 4) {
            int2 p0 = s_pair[row][j],     p1 = s_pair[row][j + 1];
            int2 p2 = s_pair[row][j + 2], p3 = s_pair[row][j + 3];
            half8 v0 = act8[p0.x * 16 + lane];
            half8 v1 = act8[p1.x * 16 + lane];
            half8 v2 = act8[p2.x * 16 + lane];
            half8 v3 = act8[p3.x * 16 + lane];
            float c0 = __int_as_float(p0.y), c1 = __int_as_float(p1.y);
            float c2 = __int_as_float(p2.y), c3 = __int_as_float(p3.y);
            #pragma unroll
            for (int t = 0; t < 8; t++) {
                acc[t] = fmaf(c0, (float)v0[t], acc[t]);
                acc[t] = fmaf(c1, (float)v1[t], acc[t]);
                acc[t] = fmaf(c2, (float)v2[t], acc[t]);
                acc[t] = fmaf(c3, (float)v3[t], acc[t]);
            }
        }
        for (; j < m; j++) {
            int2 p = s_pair[row][j];
            float cf = __int_as_float(p.y);
            half8 v = act8[p.x * 16 + lane];
            #pragma unroll
            for (int t = 0; t < 8; t++) acc[t] = fmaf(cf, (float)v[t], acc[t]);
        }
        __builtin_amdgcn_wave_barrier();
    }
    float cg = cagg[node];
    half8 o;
    #pragma unroll
    for (int t = 0; t < 8; t++) {
        int c = lane * 8 + t;
        o[t] = (_Float16)fmaf(s_bnw[c], acc[t], s_bnu[c] * cg);
    }
    ((half8*)A)[node * 16 + lane] = o;
}

// ---------------- fp16 MFMA GEMM (layers 1-3): act = rational(A @ W + bias) + stats ----------------
// 256 threads = 4 waves x 16 rows; A and W hi/lo fragments read directly from global.
__global__ __launch_bounds__(256) void gemm_mfma_kernel(const _Float16* __restrict__ A,
                                                        const _Float16* __restrict__ Whi,
                                                        const _Float16* __restrict__ Wlo,
                                                        const float* __restrict__ bias,
                                                        const float* __restrict__ rat_num,
                                                        const float* __restrict__ rat_den,
                                                        const int* __restrict__ cl_assign,
                                                        _Float16* __restrict__ act,
                                                        float* __restrict__ stat, int n) {
    __shared__ float s_num[120], s_den[80];
    __shared__ int s_cl[HID];
    __shared__ float s_bias[HID];
    __shared__ float s_sum[HID], s_sq[HID];
    int tid = threadIdx.x;
    if (tid < 120) s_num[tid] = rat_num[tid];
    if (tid < 80) s_den[tid] = rat_den[tid];
    if (tid < HID) {
        s_cl[tid] = cl_assign[tid];
        s_bias[tid] = bias[tid];
        s_sum[tid] = 0.0f; s_sq[tid] = 0.0f;
    }
    __syncthreads();

    int w = tid >> 6, lane = tid & 63;
    int quad = lane >> 4, l16 = lane & 15;
    int r0 = blockIdx.x * 64 + w * 16;

    const half8* A8 = (const half8*)A;
    const half8* Bh8 = (const half8*)Whi;
    const half8* Bl8 = (const half8*)Wlo;

    f32x4 acc[8];
    #pragma unroll
    for (int j = 0; j < 8; j++) acc[j] = (f32x4){0.f, 0.f, 0.f, 0.f};

    int rowA = r0 + l16;
    int rcA = (rowA < n) ? rowA : 0;
    #pragma unroll
    for (int kc = 0; kc < 4; kc++) {
        half8 a = A8[rcA * 16 + kc * 4 + quad];
        #pragma unroll
        for (int nt = 0; nt < 8; nt++) {
            half8 bh = Bh8[(nt * 4 + kc) * 64 + lane];
            half8 bl = Bl8[(nt * 4 + kc) * 64 + lane];
            acc[nt] = __builtin_amdgcn_mfma_f32_16x16x32_f16(a, bh, acc[nt], 0, 0, 0);
            acc[nt] = __builtin_amdgcn_mfma_f32_16x16x32_f16(a, bl, acc[nt], 0, 0, 0);
        }
    }

    // epilogue: bias + rational + fp16 store + stats (C layout: col=l16, row=quad*4+reg)
    float ps[8], pq[8];
    #pragma unroll
    for (int nt = 0; nt < 8; nt++) { ps[nt] = 0.0f; pq[nt] = 0.0f; }
    #pragma unroll
    for (int reg = 0; reg < 4; reg++) {
        int row = r0 + quad * 4 + reg;
        if (row < n) {
            #pragma unroll
            for (int nt = 0; nt < 8; nt++) {
                int col = nt * 16 + l16;
                float v = acc[nt][reg] + s_bias[col];
                float r = rational_act(v, s_num + s_cl[col] * 6, s_den + s_cl[col] * 4);
                act[row * HID + col] = (_Float16)r;
                ps[nt] += r; pq[nt] = fmaf(r, r, pq[nt]);
            }
        }
    }
    #pragma unroll
    for (int nt = 0; nt < 8; nt++) {
        int col = nt * 16 + l16;
        atomicAdd(&s_sum[col], ps[nt]);
        atomicAdd(&s_sq[col], pq[nt]);
    }
    __syncthreads();
    if (tid < HID) {
        atomicAdd(&stat[tid], s_sum[tid]);
        atomicAdd(&stat[HID + tid], s_sq[tid]);
    }
}

// ---------------- fused pool (+final BN affine from stats) + 3-stage MLP ----------------
__global__ __launch_bounds__(256) void poolmlp_kernel(const _Float16* __restrict__ act,
                                                      const int* __restrict__ gstart,
                                                      const int* __restrict__ gend,
                                                      const float* __restrict__ stat,
                                                      const float* __restrict__ g3,
                                                      const float* __restrict__ be3,
                                                      const float* __restrict__ HW1,
                                                      const float* __restrict__ Hb1,
                                                      const float* __restrict__ HW2,
                                                      const float* __restrict__ Hb2,
                                                      const float* __restrict__ HW3,
                                                      const float* __restrict__ Hb3,
                                                      float* __restrict__ out, int n) {
    __shared__ float red[16][HID];
    __shared__ float s_pool[HID];
    __shared__ float s_z[HID];
    int gi = blockIdx.x;
    int tid = threadIdx.x;
    int rg = tid >> 4, lane = tid & 15;
    int s = gstart[gi], e = gend[gi];
    const half8* act8 = (const half8*)act;
    float a[8];
    #pragma unroll
    for (int t = 0; t < 8; t++) a[t] = 0.0f;
    for (int r = s + rg; r < e; r += 16) {
        half8 v = act8[r * 16 + lane];
        #pragma unroll
        for (int t = 0; t < 8; t++) a[t] += (float)v[t];
    }
    #pragma unroll
    for (int t = 0; t < 8; t++) red[rg][lane * 8 + t] = a[t];
    __syncthreads();
    if (tid < HID) {
        float tot = 0.0f;
        #pragma unroll
        for (int i = 0; i < 16; i++) tot += red[i][tid];
        int cnt = e - s;
        float pooled = 0.0f;
        if (cnt > 0) {
            float inv_n = 1.0f / (float)n;
            float mean = stat[tid] * inv_n;
            float var = stat[HID + tid] * inv_n - mean * mean;
            float w = g3[tid] * rsqrtf(var + 1e-5f);
            float u = be3[tid] - mean * w;
            pooled = fmaf(w, tot / (float)cnt, u);
        }
        s_pool[tid] = pooled;
    }
    __syncthreads();
    if (tid < HID) {
        float acc = Hb1[tid];
        #pragma unroll 8
        for (int k = 0; k < HID; k++) acc = fmaf(s_pool[k], HW1[k * HID + tid], acc);
        s_z[tid] = 0.5f * acc * (1.0f + erff(acc * 0.70710678118654752f));
    }
    __syncthreads();
    if (tid < HID) {
        float acc = Hb2[tid];
        #pragma unroll 8
        for (int k = 0; k < HID; k++) acc = fmaf(s_z[k], HW2[k * HID + tid], acc);
        s_pool[tid] = 0.5f * acc * (1.0f + erff(acc * 0.70710678118654752f));
    }
    __syncthreads();
    if (tid < OUTF) {
        float acc = Hb3[tid];
        #pragma unroll 8
        for (int k = 0; k < HID; k++) acc = fmaf(s_pool[k], HW3[k * OUTF + tid], acc);
        out[gi * OUTF + tid] = acc;
    }
}

extern "C" void kernel_launch(void* const* d_in, const int* in_sizes, int n_in,
                              void* d_out, int out_size, void* d_ws, size_t ws_size,
                              hipStream_t stream) {
    const float* x          = (const float*)d_in[0];
    const int*   edge_index = (const int*)d_in[1];
    const int*   batch      = (const int*)d_in[2];
    const float* W[4]  = {(const float*)d_in[3], (const float*)d_in[7], (const float*)d_in[11], (const float*)d_in[15]};
    const float* bL[4] = {(const float*)d_in[4], (const float*)d_in[8], (const float*)d_in[12], (const float*)d_in[16]};
    const float* gL[4] = {(const float*)d_in[5], (const float*)d_in[9], (const float*)d_in[13], (const float*)d_in[17]};
    const float* beL[4]= {(const float*)d_in[6], (const float*)d_in[10], (const float*)d_in[14], (const float*)d_in[18]};
    const float* rat_num = (const float*)d_in[19];
    const float* rat_den = (const float*)d_in[20];
    const int*   cl_assign = (const int*)d_in[21];
    const float* HW1 = (const float*)d_in[22];
    const float* Hb1 = (const float*)d_in[23];
    const float* HW2 = (const float*)d_in[24];
    const float* Hb2 = (const float*)d_in[25];
    const float* HW3 = (const float*)d_in[26];
    const float* Hb3 = (const float*)d_in[27];
    float* out = (float*)d_out;

    const int N = in_sizes[0] / INF;
    const int E = in_sizes[1] / 2;
    const int NB = (N + 1023) / 1024;

    // ---- workspace layout (dword offsets) ----
    char* wsb = (char*)d_ws;
    size_t o = 0;
    #define ALIGN16 o = (o + 3) & ~(size_t)3;
    int*   cnt     = (int*)(wsb + o * 4);  o += N; ALIGN16          // zeroed; reused as cagg
    int*   gstart  = (int*)(wsb + o * 4);  o += GRP;                // zeroed
    int*   gend    = (int*)(wsb + o * 4);  o += GRP;                // zeroed
    float* bnstat  = (float*)(wsb + o * 4); o += 4 * 256;           // zeroed
    size_t zero_elems = o;
    int*   bsum    = (int*)(wsb + o * 4);  o += ((NB + 63) & ~63); ALIGN16
    int*   cursor  = (int*)(wsb + o * 4);  o += N; ALIGN16
    int*   row_ptr = (int*)(wsb + o * 4);  o += N + 1; ALIGN16
    float* dinv    = (float*)(wsb + o * 4); o += N; ALIGN16
    int2*  csr     = (int2*)(wsb + o * 4);  o += 2 * (size_t)E; ALIGN16
    float* aggX    = (float*)(wsb + o * 4); o += (size_t)N * INF; ALIGN16
    _Float16* WhiAll = (_Float16*)(wsb + o * 4); o += 4 * HID * HID / 2; ALIGN16
    _Float16* WloAll = (_Float16*)(wsb + o * 4); o += 4 * HID * HID / 2; ALIGN16
    _Float16* act_h  = (_Float16*)(wsb + o * 4); o += (size_t)N * HID / 2; ALIGN16
    _Float16* A_h    = (_Float16*)(wsb + o * 4); o += (size_t)N * HID / 2;
    float* cagg = (float*)cnt;

    hipMemsetAsync(d_ws, 0, zero_elems * 4, stream);

    int eb = (E + 255) / 256;
    hist_prepw_kernel<<<eb, 256, 0, stream>>>(edge_index, cnt, E, W[1], W[2], W[3],
                                              WhiAll, WloAll);
    scanA_kernel<<<NB, 256, 0, stream>>>(cnt, bsum, N);
    scanB_kernel<<<1, 64, 0, stream>>>(bsum, row_ptr, NB, N);
    scanC_kernel<<<NB, 256, 0, stream>>>(cnt, bsum, batch, row_ptr, cursor, dinv,
                                         gstart, gend, N);
    fill_kernel<<<eb, 256, 0, stream>>>(edge_index, cursor, dinv, csr, E);

    // layer 0
    aggx_kernel<<<(N + 15) / 16, 256, 0, stream>>>(x, row_ptr, csr, dinv, aggX, cagg, N);
    gemm0_fused_kernel<<<1024, 256, 0, stream>>>(aggX, W[0], bL[0], rat_num, rat_den,
                                                 cl_assign, act_h, bnstat, N);

    // layers 1-3: agg (act -> A, with BN-from-stats) then MFMA gemm (A -> act)
    int agg_grid = (N + 15) / 16;
    int gemm_grid = (N + 63) / 64;
    for (int l = 1; l < 4; l++) {
        agg_kernel<<<agg_grid, 256, 0, stream>>>(act_h, row_ptr, csr, dinv, cagg,
                                                 bnstat + (l - 1) * 256,
                                                 gL[l - 1], beL[l - 1], A_h, N);
        gemm_mfma_kernel<<<gemm_grid, 256, 0, stream>>>(A_h,
                                                        WhiAll + (size_t)l * HID * HID,
                                                        WloAll + (size_t)l * HID * HID, bL[l],
                                                        rat_num, rat_den, cl_assign,
                                                        act_h, bnstat + l * 256, N);
    }
    poolmlp_kernel<<<GRP, 256, 0, stream>>>(act_h, gstart, gend, bnstat + 3 * 256,
                                            gL[3], beL[3], HW1, Hb1, HW2, Hb2, HW3, Hb3,
                                            out, N);
}

// Round 11
// 525.003 us; speedup vs baseline: 1.0849x; 1.0368x over previous
//
#include <hip/hip_runtime.h>
#include <math.h>

#define HID 128
#define GRP 256
#define INF 9
#define OUTF 10

typedef _Float16 half8 __attribute__((ext_vector_type(8)));
typedef __attribute__((ext_vector_type(4))) float f32x4;

// ---------------- histogram over dst + fold in W-prep (layers 1..3) ----------------
// W fragment order: off = (((nt*4+kc)*4+quad)*16 + l16)*8 + j ; n=nt*16+l16, k=kc*32+quad*8+j
__global__ void hist_prepw_kernel(const int* __restrict__ ei, int* __restrict__ cnt, int E,
                                  const float* __restrict__ W1, const float* __restrict__ W2,
                                  const float* __restrict__ W3,
                                  _Float16* __restrict__ Whi, _Float16* __restrict__ Wlo) {
    int e = blockIdx.x * 256 + threadIdx.x;
    if (e < E) atomicAdd(&cnt[ei[E + e]], 1);
    if (blockIdx.x < 192) {
        int l = blockIdx.x >> 6;                       // 0..2 -> layers 1..3
        int idx = (blockIdx.x & 63) * 256 + threadIdx.x;   // 0..16383
        const float* W = (l == 0) ? W1 : (l == 1) ? W2 : W3;
        int nn = idx >> 7, k = idx & 127;
        float w = W[k * HID + nn];
        _Float16 hi = (_Float16)w;
        _Float16 lo = (_Float16)(w - (float)hi);
        int nt = nn >> 4, l16 = nn & 15;
        int kc = k >> 5, quad = (k >> 3) & 3, j = k & 7;
        size_t off = (size_t)(l + 1) * HID * HID +
                     ((((nt * 4 + kc) * 4 + quad) * 16 + l16) * 8 + j);
        Whi[off] = hi;
        Wlo[off] = lo;
    }
}

// ---------------- parallel scan phase A: per-1024-chunk sums ----------------
__global__ __launch_bounds__(256) void scanA_kernel(const int* __restrict__ cnt,
                                                    int* __restrict__ bsum, int n) {
    int tid = threadIdx.x;
    int base = blockIdx.x * 1024 + tid * 4;
    int s = 0;
    #pragma unroll
    for (int i = 0; i < 4; i++) s += (base + i < n) ? cnt[base + i] : 0;
    #pragma unroll
    for (int off = 32; off > 0; off >>= 1) s += __shfl_down(s, off);
    __shared__ int ws[4];
    if ((tid & 63) == 0) ws[tid >> 6] = s;
    __syncthreads();
    if (tid == 0) bsum[blockIdx.x] = ws[0] + ws[1] + ws[2] + ws[3];
}

// ---------------- phase B: exclusive scan of block sums (in place) ----------------
__global__ void scanB_kernel(int* __restrict__ bsum, int* __restrict__ row_ptr,
                             int nb, int n) {
    int lane = threadIdx.x;   // 64 threads
    int carry = 0;
    for (int base = 0; base < nb; base += 64) {
        int v = (base + lane < nb) ? bsum[base + lane] : 0;
        int ps = v;
        #pragma unroll
        for (int off = 1; off < 64; off <<= 1) {
            int t = __shfl_up(ps, off);
            if (lane >= off) ps += t;
        }
        if (base + lane < nb) bsum[base + lane] = carry + ps - v;
        carry += __shfl(ps, 63);
    }
    if (lane == 0) row_ptr[n] = carry;
}

// ---------------- phase C: local scan + row_ptr/cursor/dinv + graph bounds ----------------
__global__ __launch_bounds__(256) void scanC_kernel(const int* __restrict__ cnt,
                                                    const int* __restrict__ bsum,
                                                    const int* __restrict__ batch,
                                                    int* __restrict__ row_ptr,
                                                    int* __restrict__ cursor,
                                                    float* __restrict__ dinv,
                                                    int* __restrict__ gstart,
                                                    int* __restrict__ gend, int n) {
    int tid = threadIdx.x;
    int lane = tid & 63, wid = tid >> 6;
    int idx0 = blockIdx.x * 1024 + tid * 4;
    int v[4];
    #pragma unroll
    for (int i = 0; i < 4; i++) v[i] = (idx0 + i < n) ? cnt[idx0 + i] : 0;
    int s = v[0] + v[1] + v[2] + v[3];
    int ps = s;
    #pragma unroll
    for (int off = 1; off < 64; off <<= 1) {
        int t = __shfl_up(ps, off);
        if (lane >= off) ps += t;
    }
    __shared__ int wsum[4];
    if (lane == 63) wsum[wid] = ps;
    __syncthreads();
    int woff = 0;
    #pragma unroll
    for (int i = 0; i < 4; i++) if (i < wid) woff += wsum[i];
    int run = bsum[blockIdx.x] + woff + (ps - s);
    #pragma unroll
    for (int i = 0; i < 4; i++) {
        int idx = idx0 + i;
        if (idx < n) {
            row_ptr[idx] = run;
            cursor[idx] = run;
            dinv[idx] = rsqrtf((float)(v[i] + 1));
            run += v[i];
            int b = batch[idx];
            if (idx == 0 || batch[idx - 1] != b) gstart[b] = idx;
            if (idx == n - 1 || batch[idx + 1] != b) gend[b] = idx + 1;
        }
    }
}

// ---------------- CSR fill: (src, coef) packed as int2, one 8B scatter ----------------
__global__ void fill_kernel(const int* __restrict__ ei, int* __restrict__ cursor,
                            const float* __restrict__ dinv,
                            int2* __restrict__ csr, int E) {
    int e = blockIdx.x * blockDim.x + threadIdx.x;
    if (e >= E) return;
    int s = ei[e], d = ei[E + e];
    int pos = atomicAdd(&cursor[d], 1);
    csr[pos] = make_int2(s, __float_as_int(dinv[s] * dinv[d]));
}

// ---------------- rational activation, transposed coeff layout [coef][cluster] ----------------
// nt_ = s_numT + cl (stride 20 between coefs), dt_ = s_denT + cl.
__device__ __forceinline__ float rational_act_t(float xv, const float* __restrict__ nt_,
                                                const float* __restrict__ dt_) {
    float P = nt_[100];
    P = fmaf(P, xv, nt_[80]); P = fmaf(P, xv, nt_[60]); P = fmaf(P, xv, nt_[40]);
    P = fmaf(P, xv, nt_[20]); P = fmaf(P, xv, nt_[0]);
    float Q = dt_[60];
    Q = fmaf(Q, xv, dt_[40]); Q = fmaf(Q, xv, dt_[20]); Q = fmaf(Q, xv, dt_[0]);
    Q *= xv;
    return P / (1.0f + fabsf(Q));
}

// ---------------- aggregate x (9 channels) + cagg ----------------
__global__ __launch_bounds__(256) void aggx_kernel(const float* __restrict__ x,
                                                   const int* __restrict__ row_ptr,
                                                   const int2* __restrict__ csr,
                                                   const float* __restrict__ dinv,
                                                   float* __restrict__ aggX,
                                                   float* __restrict__ cagg, int n) {
    int tid = threadIdx.x;
    int node = blockIdx.x * 16 + (tid >> 4);
    int lane = tid & 15;
    if (node >= n) return;
    float di = dinv[node];
    float self = di * di;
    float acc = (lane < INF) ? x[node * INF + lane] * self : 0.0f;
    float cfs = self;
    int beg = row_ptr[node], end = row_ptr[node + 1];
    for (int j = beg; j < end; j++) {
        int2 p = csr[j];
        float cf = __int_as_float(p.y);
        cfs += cf;
        if (lane < INF) acc = fmaf(cf, x[p.x * INF + lane], acc);
    }
    if (lane < INF) aggX[node * INF + lane] = acc;
    if (lane == 0) cagg[node] = cfs;
}

// ---------------- layer-0: aggX(Nx9) @ W0 + b0 -> rational -> act(fp16) + stats ----------------
__global__ __launch_bounds__(256) void gemm0_fused_kernel(const float* __restrict__ aggX,
                                                          const float* __restrict__ W0,
                                                          const float* __restrict__ b0,
                                                          const float* __restrict__ rat_num,
                                                          const float* __restrict__ rat_den,
                                                          const int* __restrict__ cl_assign,
                                                          _Float16* __restrict__ act,
                                                          float* __restrict__ stat, int n) {
    __shared__ float Ws[INF * HID];
    __shared__ float s_numT[120], s_denT[80];
    __shared__ int s_cl[HID];
    __shared__ float s_b[HID];
    __shared__ float s_sum[HID], s_sq[HID];
    int tid = threadIdx.x;
    for (int i = tid; i < INF * HID; i += 256) Ws[i] = W0[i];
    if (tid < 120) s_numT[(tid % 6) * 20 + tid / 6] = rat_num[tid];
    if (tid < 80) s_denT[(tid % 4) * 20 + tid / 4] = rat_den[tid];
    if (tid < HID) {
        s_cl[tid] = cl_assign[tid];
        s_b[tid] = b0[tid];
        s_sum[tid] = 0.0f; s_sq[tid] = 0.0f;
    }
    __syncthreads();
    int c = tid & 127;
    int half = tid >> 7;
    const float* nt_ = s_numT + s_cl[c];
    const float* dt_ = s_denT + s_cl[c];
    float psum = 0.0f, psq = 0.0f;
    for (int node = blockIdx.x * 2 + half; node < n; node += gridDim.x * 2) {
        float acc = s_b[c];
        #pragma unroll
        for (int k = 0; k < INF; k++) acc = fmaf(aggX[node * INF + k], Ws[k * HID + c], acc);
        float r = rational_act_t(acc, nt_, dt_);
        act[node * HID + c] = (_Float16)r;
        psum += r; psq = fmaf(r, r, psq);
    }
    atomicAdd(&s_sum[c], psum);
    atomicAdd(&s_sq[c], psq);
    __syncthreads();
    if (tid < HID) {
        atomicAdd(&stat[tid], s_sum[tid]);
        atomicAdd(&stat[HID + tid], s_sq[tid]);
    }
}

// ---------------- standalone gather-aggregate (fp16) + inline BN affine -> A (fp16) ----------------
// 16 nodes/block x 16 lanes, 256 threads, 8 loads in flight. Unfused from GEMM (r6-r9 lesson).
__global__ __launch_bounds__(256) void agg_kernel(const _Float16* __restrict__ act,
                                                  const int* __restrict__ row_ptr,
                                                  const int2* __restrict__ csr,
                                                  const float* __restrict__ dinv,
                                                  const float* __restrict__ cagg,
                                                  const float* __restrict__ statPrev,
                                                  const float* __restrict__ gPrev,
                                                  const float* __restrict__ bePrev,
                                                  _Float16* __restrict__ A, int n) {
    __shared__ float s_bnw[HID], s_bnu[HID];
    __shared__ int2 s_pair[16][16];
    int tid = threadIdx.x;
    if (tid < HID) {
        float inv_n = 1.0f / (float)n;
        float mean = statPrev[tid] * inv_n;
        float var = statPrev[HID + tid] * inv_n - mean * mean;
        float w = gPrev[tid] * rsqrtf(var + 1e-5f);
        s_bnw[tid] = w;
        s_bnu[tid] = bePrev[tid] - mean * w;
    }
    __syncthreads();
    int row = tid >> 4, lane = tid & 15;
    int node = blockIdx.x * 16 + row;
    if (node >= n) return;
    const half8* act8 = (const half8*)act;
    float di = dinv[node];
    float selfc = di * di;
    half8 sv = act8[node * 16 + lane];
    float acc[8];
    #pragma unroll
    for (int t = 0; t < 8; t++) acc[t] = (float)sv[t] * selfc;
    int beg = row_ptr[node], end = row_ptr[node + 1];
    for (int base = beg; base < end; base += 16) {
        int m = end - base; if (m > 16) m = 16;
        if (lane < m) s_pair[row][lane] = csr[base + lane];
        __builtin_amdgcn_wave_barrier();
        int j = 0;
        for (; j + 8 <= m; j += 8) {
            int2 p0 = s_pair[row][j],     p1 = s_pair[row][j + 1];
            int2 p2 = s_pair[row][j + 2], p3 = s_pair[row][j + 3];
            int2 p4 = s_pair[row][j + 4], p5 = s_pair[row][j + 5];
            int2 p6 = s_pair[row][j + 6], p7 = s_pair[row][j + 7];
            half8 v0 = act8[p0.x * 16 + lane];
            half8 v1 = act8[p1.x * 16 + lane];
            half8 v2 = act8[p2.x * 16 + lane];
            half8 v3 = act8[p3.x * 16 + lane];
            half8 v4 = act8[p4.x * 16 + lane];
            half8 v5 = act8[p5.x * 16 + lane];
            half8 v6 = act8[p6.x * 16 + lane];
            half8 v7 = act8[p7.x * 16 + lane];
            float c0 = __int_as_float(p0.y), c1 = __int_as_float(p1.y);
            float c2 = __int_as_float(p2.y), c3 = __int_as_float(p3.y);
            float c4 = __int_as_float(p4.y), c5 = __int_as_float(p5.y);
            float c6 = __int_as_float(p6.y), c7 = __int_as_float(p7.y);
            #pragma unroll
            for (int t = 0; t < 8; t++) {
                acc[t] = fmaf(c0, (float)v0[t], acc[t]);
                acc[t] = fmaf(c1, (float)v1[t], acc[t]);
                acc[t] = fmaf(c2, (float)v2[t], acc[t]);
                acc[t] = fmaf(c3, (float)v3[t], acc[t]);
                acc[t] = fmaf(c4, (float)v4[t], acc[t]);
                acc[t] = fmaf(c5, (float)v5[t], acc[t]);
                acc[t] = fmaf(c6, (float)v6[t], acc[t]);
                acc[t] = fmaf(c7, (float)v7[t], acc[t]);
            }
        }
        for (; j + 4 <= m; j += 4) {
            int2 p0 = s_pair[row][j],     p1 = s_pair[row][j + 1];
            int2 p2 = s_pair[row][j + 2], p3 = s_pair[row][j + 3];
            half8 v0 = act8[p0.x * 16 + lane];
            half8 v1 = act8[p1.x * 16 + lane];
            half8 v2 = act8[p2.x * 16 + lane];
            half8 v3 = act8[p3.x * 16 + lane];
            float c0 = __int_as_float(p0.y), c1 = __int_as_float(p1.y);
            float c2 = __int_as_float(p2.y), c3 = __int_as_float(p3.y);
            #pragma unroll
            for (int t = 0; t < 8; t++) {
                acc[t] = fmaf(c0, (float)v0[t], acc[t]);
                acc[t] = fmaf(c1, (float)v1[t], acc[t]);
                acc[t] = fmaf(c2, (float)v2[t], acc[t]);
                acc[t] = fmaf(c3, (float)v3[t], acc[t]);
            }
        }
        for (; j < m; j++) {
            int2 p = s_pair[row][j];
            float cf = __int_as_float(p.y);
            half8 v = act8[p.x * 16 + lane];
            #pragma unroll
            for (int t = 0; t < 8; t++) acc[t] = fmaf(cf, (float)v[t], acc[t]);
        }
        __builtin_amdgcn_wave_barrier();
    }
    float cg = cagg[node];
    half8 o;
    #pragma unroll
    for (int t = 0; t < 8; t++) {
        int c = lane * 8 + t;
        o[t] = (_Float16)fmaf(s_bnw[c], acc[t], s_bnu[c] * cg);
    }
    ((half8*)A)[node * 16 + lane] = o;
}

// ---------------- fp16 MFMA GEMM (layers 1-3): act = rational(A @ W + bias) + stats ----------------
// 256 threads = 4 waves x 16 rows (64 rows/block). W staged in LDS per block,
// double-buffered over kc (r10 lesson: per-wave global W loads were 1:1 with MFMA and
// latency-bound at 50 µs). Output coalesced via LDS transpose.
__global__ __launch_bounds__(256) void gemm_mfma_kernel(const _Float16* __restrict__ A,
                                                        const _Float16* __restrict__ Whi,
                                                        const _Float16* __restrict__ Wlo,
                                                        const float* __restrict__ bias,
                                                        const float* __restrict__ rat_num,
                                                        const float* __restrict__ rat_den,
                                                        const int* __restrict__ cl_assign,
                                                        _Float16* __restrict__ act,
                                                        float* __restrict__ stat, int n) {
    __shared__ _Float16 Wlds[2][8192];   // per kc: [hi 512 | lo 512] granules of half8
    __shared__ float s_numT[120], s_denT[80];
    __shared__ int s_cl[HID];
    __shared__ float s_bias[HID];
    __shared__ float s_sum[HID], s_sq[HID];
    int tid = threadIdx.x;
    if (tid < 120) s_numT[(tid % 6) * 20 + tid / 6] = rat_num[tid];
    if (tid < 80) s_denT[(tid % 4) * 20 + tid / 4] = rat_den[tid];
    if (tid < HID) {
        s_cl[tid] = cl_assign[tid];
        s_bias[tid] = bias[tid];
        s_sum[tid] = 0.0f; s_sq[tid] = 0.0f;
    }

    const half8* BhG = (const half8*)Whi;
    const half8* BlG = (const half8*)Wlo;
    // stage W fragments for one kc into LDS buffer b (coalesced, conflict-free)
    auto stage = [&](int kc, int b) {
        half8* dst = (half8*)Wlds[b];
        #pragma unroll
        for (int i = 0; i < 4; i++) {
            int idx = tid + i * 256;          // 0..1023 granules
            int j = idx & 511;
            int so = ((j >> 6) * 4 + kc) * 64 + (j & 63);
            dst[idx] = (idx < 512) ? BhG[so] : BlG[so];
        }
    };
    stage(0, 0);

    int w = tid >> 6, lane = tid & 63;
    int quad = lane >> 4, l16 = lane & 15;
    int r0 = blockIdx.x * 64;
    int rowA = r0 + w * 16 + l16;
    int rcA = (rowA < n) ? rowA : 0;

    // preload all A fragments (4 global loads, issued up front)
    const half8* A8 = (const half8*)A;
    half8 aReg[4];
    #pragma unroll
    for (int kc = 0; kc < 4; kc++) aReg[kc] = A8[rcA * 16 + kc * 4 + quad];

    f32x4 acc[8];
    #pragma unroll
    for (int j = 0; j < 8; j++) acc[j] = (f32x4){0.f, 0.f, 0.f, 0.f};

    #pragma unroll
    for (int kc = 0; kc < 4; kc++) {
        __syncthreads();                       // staged buffer ready
        if (kc < 3) stage(kc + 1, (kc + 1) & 1);
        const half8* Wb = (const half8*)Wlds[kc & 1];
        half8 a = aReg[kc];
        #pragma unroll
        for (int nt = 0; nt < 8; nt++) {
            half8 bh = Wb[nt * 64 + lane];
            half8 bl = Wb[512 + nt * 64 + lane];
            acc[nt] = __builtin_amdgcn_mfma_f32_16x16x32_f16(a, bh, acc[nt], 0, 0, 0);
            acc[nt] = __builtin_amdgcn_mfma_f32_16x16x32_f16(a, bl, acc[nt], 0, 0, 0);
        }
    }
    __syncthreads();                           // all reads of Wlds done

    // epilogue: bias + rational + stats; stage fp16 C tile in LDS (reuse Wlds[0])
    _Float16* Clds = Wlds[0];                  // 64 rows x 128 cols
    float ps[8], pq[8];
    #pragma unroll
    for (int nt = 0; nt < 8; nt++) { ps[nt] = 0.0f; pq[nt] = 0.0f; }
    #pragma unroll
    for (int reg = 0; reg < 4; reg++) {
        int lrow = w * 16 + quad * 4 + reg;
        if (r0 + lrow < n) {
            #pragma unroll
            for (int nt = 0; nt < 8; nt++) {
                int col = nt * 16 + l16;
                float v = acc[nt][reg] + s_bias[col];
                float r = rational_act_t(v, s_numT + s_cl[col], s_denT + s_cl[col]);
                Clds[lrow * 128 + col] = (_Float16)r;
                ps[nt] += r; pq[nt] = fmaf(r, r, pq[nt]);
            }
        }
    }
    #pragma unroll
    for (int nt = 0; nt < 8; nt++) {
        int col = nt * 16 + l16;
        atomicAdd(&s_sum[col], ps[nt]);
        atomicAdd(&s_sq[col], pq[nt]);
    }
    __syncthreads();
    // coalesced store: thread -> (row = tid>>2, 64B segment = tid&3)
    {
        int row = tid >> 2, seg = tid & 3;
        int grow = r0 + row;
        if (grow < n) {
            half8* dst = (half8*)&act[(size_t)grow * HID];
            const half8* src = (const half8*)&Clds[row * 128];
            #pragma unroll
            for (int k = 0; k < 4; k++) dst[seg * 4 + k] = src[seg * 4 + k];
        }
    }
    if (tid < HID) {
        atomicAdd(&stat[tid], s_sum[tid]);
        atomicAdd(&stat[HID + tid], s_sq[tid]);
    }
}

// ---------------- fused pool (+final BN affine from stats) + 3-stage MLP ----------------
__global__ __launch_bounds__(256) void poolmlp_kernel(const _Float16* __restrict__ act,
                                                      const int* __restrict__ gstart,
                                                      const int* __restrict__ gend,
                                                      const float* __restrict__ stat,
                                                      const float* __restrict__ g3,
                                                      const float* __restrict__ be3,
                                                      const float* __restrict__ HW1,
                                                      const float* __restrict__ Hb1,
                                                      const float* __restrict__ HW2,
                                                      const float* __restrict__ Hb2,
                                                      const float* __restrict__ HW3,
                                                      const float* __restrict__ Hb3,
                                                      float* __restrict__ out, int n) {
    __shared__ float red[16][HID];
    __shared__ float s_pool[HID];
    __shared__ float s_z[HID];
    int gi = blockIdx.x;
    int tid = threadIdx.x;
    int rg = tid >> 4, lane = tid & 15;
    int s = gstart[gi], e = gend[gi];
    const half8* act8 = (const half8*)act;
    float a[8];
    #pragma unroll
    for (int t = 0; t < 8; t++) a[t] = 0.0f;
    for (int r = s + rg; r < e; r += 16) {
        half8 v = act8[r * 16 + lane];
        #pragma unroll
        for (int t = 0; t < 8; t++) a[t] += (float)v[t];
    }
    #pragma unroll
    for (int t = 0; t < 8; t++) red[rg][lane * 8 + t] = a[t];
    __syncthreads();
    if (tid < HID) {
        float tot = 0.0f;
        #pragma unroll
        for (int i = 0; i < 16; i++) tot += red[i][tid];
        int cnt = e - s;
        float pooled = 0.0f;
        if (cnt > 0) {
            float inv_n = 1.0f / (float)n;
            float mean = stat[tid] * inv_n;
            float var = stat[HID + tid] * inv_n - mean * mean;
            float w = g3[tid] * rsqrtf(var + 1e-5f);
            float u = be3[tid] - mean * w;
            pooled = fmaf(w, tot / (float)cnt, u);
        }
        s_pool[tid] = pooled;
    }
    __syncthreads();
    if (tid < HID) {
        float acc = Hb1[tid];
        #pragma unroll 8
        for (int k = 0; k < HID; k++) acc = fmaf(s_pool[k], HW1[k * HID + tid], acc);
        s_z[tid] = 0.5f * acc * (1.0f + erff(acc * 0.70710678118654752f));
    }
    __syncthreads();
    if (tid < HID) {
        float acc = Hb2[tid];
        #pragma unroll 8
        for (int k = 0; k < HID; k++) acc = fmaf(s_z[k], HW2[k * HID + tid], acc);
        s_pool[tid] = 0.5f * acc * (1.0f + erff(acc * 0.70710678118654752f));
    }
    __syncthreads();
    if (tid < OUTF) {
        float acc = Hb3[tid];
        #pragma unroll 8
        for (int k = 0; k < HID; k++) acc = fmaf(s_pool[k], HW3[k * OUTF + tid], acc);
        out[gi * OUTF + tid] = acc;
    }
}

extern "C" void kernel_launch(void* const* d_in, const int* in_sizes, int n_in,
                              void* d_out, int out_size, void* d_ws, size_t ws_size,
                              hipStream_t stream) {
    const float* x          = (const float*)d_in[0];
    const int*   edge_index = (const int*)d_in[1];
    const int*   batch      = (const int*)d_in[2];
    const float* W[4]  = {(const float*)d_in[3], (const float*)d_in[7], (const float*)d_in[11], (const float*)d_in[15]};
    const float* bL[4] = {(const float*)d_in[4], (const float*)d_in[8], (const float*)d_in[12], (const float*)d_in[16]};
    const float* gL[4] = {(const float*)d_in[5], (const float*)d_in[9], (const float*)d_in[13], (const float*)d_in[17]};
    const float* beL[4]= {(const float*)d_in[6], (const float*)d_in[10], (const float*)d_in[14], (const float*)d_in[18]};
    const float* rat_num = (const float*)d_in[19];
    const float* rat_den = (const float*)d_in[20];
    const int*   cl_assign = (const int*)d_in[21];
    const float* HW1 = (const float*)d_in[22];
    const float* Hb1 = (const float*)d_in[23];
    const float* HW2 = (const float*)d_in[24];
    const float* Hb2 = (const float*)d_in[25];
    const float* HW3 = (const float*)d_in[26];
    const float* Hb3 = (const float*)d_in[27];
    float* out = (float*)d_out;

    const int N = in_sizes[0] / INF;
    const int E = in_sizes[1] / 2;
    const int NB = (N + 1023) / 1024;

    // ---- workspace layout (dword offsets) ----
    char* wsb = (char*)d_ws;
    size_t o = 0;
    #define ALIGN16 o = (o + 3) & ~(size_t)3;
    int*   cnt     = (int*)(wsb + o * 4);  o += N; ALIGN16          // zeroed; reused as cagg
    int*   gstart  = (int*)(wsb + o * 4);  o += GRP;                // zeroed
    int*   gend    = (int*)(wsb + o * 4);  o += GRP;                // zeroed
    float* bnstat  = (float*)(wsb + o * 4); o += 4 * 256;           // zeroed
    size_t zero_elems = o;
    int*   bsum    = (int*)(wsb + o * 4);  o += ((NB + 63) & ~63); ALIGN16
    int*   cursor  = (int*)(wsb + o * 4);  o += N; ALIGN16
    int*   row_ptr = (int*)(wsb + o * 4);  o += N + 1; ALIGN16
    float* dinv    = (float*)(wsb + o * 4); o += N; ALIGN16
    int2*  csr     = (int2*)(wsb + o * 4);  o += 2 * (size_t)E; ALIGN16
    float* aggX    = (float*)(wsb + o * 4); o += (size_t)N * INF; ALIGN16
    _Float16* WhiAll = (_Float16*)(wsb + o * 4); o += 4 * HID * HID / 2; ALIGN16
    _Float16* WloAll = (_Float16*)(wsb + o * 4); o += 4 * HID * HID / 2; ALIGN16
    _Float16* act_h  = (_Float16*)(wsb + o * 4); o += (size_t)N * HID / 2; ALIGN16
    _Float16* A_h    = (_Float16*)(wsb + o * 4); o += (size_t)N * HID / 2;
    float* cagg = (float*)cnt;

    hipMemsetAsync(d_ws, 0, zero_elems * 4, stream);

    int eb = (E + 255) / 256;
    hist_prepw_kernel<<<eb, 256, 0, stream>>>(edge_index, cnt, E, W[1], W[2], W[3],
                                              WhiAll, WloAll);
    scanA_kernel<<<NB, 256, 0, stream>>>(cnt, bsum, N);
    scanB_kernel<<<1, 64, 0, stream>>>(bsum, row_ptr, NB, N);
    scanC_kernel<<<NB, 256, 0, stream>>>(cnt, bsum, batch, row_ptr, cursor, dinv,
                                         gstart, gend, N);
    fill_kernel<<<eb, 256, 0, stream>>>(edge_index, cursor, dinv, csr, E);

    // layer 0
    aggx_kernel<<<(N + 15) / 16, 256, 0, stream>>>(x, row_ptr, csr, dinv, aggX, cagg, N);
    gemm0_fused_kernel<<<1024, 256, 0, stream>>>(aggX, W[0], bL[0], rat_num, rat_den,
                                                 cl_assign, act_h, bnstat, N);

    // layers 1-3: agg (act -> A, with BN-from-stats) then MFMA gemm (A -> act)
    int agg_grid = (N + 15) / 16;
    int gemm_grid = (N + 63) / 64;
    for (int l = 1; l < 4; l++) {
        agg_kernel<<<agg_grid, 256, 0, stream>>>(act_h, row_ptr, csr, dinv, cagg,
                                                 bnstat + (l - 1) * 256,
                                                 gL[l - 1], beL[l - 1], A_h, N);
        gemm_mfma_kernel<<<gemm_grid, 256, 0, stream>>>(A_h,
                                                        WhiAll + (size_t)l * HID * HID,
                                                        WloAll + (size_t)l * HID * HID, bL[l],
                                                        rat_num, rat_den, cl_assign,
                                                        act_h, bnstat + l * 256, N);
    }
    poolmlp_kernel<<<GRP, 256, 0, stream>>>(act_h, gstart, gend, bnstat + 3 * 256,
                                            gL[3], beL[3], HW1, Hb1, HW2, Hb2, HW3, Hb3,
                                            out, N);
}